// Round 9
// baseline (142.067 us; speedup 1.0000x reference)
//
#include <hip/hip_runtime.h>

// DP5 integrator, MI355X. fp32 in/out. Rank-128 recursion vs G'=-256·(W@U).
// R21b: 4-warp (256-thread) blocks; each warp owns TWO 16-col G groups
// (32 cols), each lane owns 4 P-cols. Mechanism: recursion per-stage cost is
// the post-barrier ds_read burst (all waves read the SAME P-tile fragments;
// 8 warps = 8x redundancy). Halving warp count halves the burst and the
// phase-1 ds_writes (b64 packs). Same math per value.
// R21b fixes R21's projection T-write transpose: fragment reg r of group g
// at lane (q,c16) holds proj[tile_row 4q+r][rank_col (2w+g)*16+c16]
// (verified against R15's shfl+bounce semantics) -> scalar writes with
// row = 4q+r (x: q<2 a-chain; v: q>=2 a-chain; f: q<2 b-chain).
// Kept: fused k_prep, DPP swap8 combine, stagger, coalesced drain.

typedef _Float16 v8h __attribute__((ext_vector_type(8)));
typedef float v4f __attribute__((ext_vector_type(4)));
typedef unsigned int u32;
typedef unsigned long long u64;

#define MFMAH __builtin_amdgcn_mfma_f32_16x16x32_f16
#define INV2048 4.8828125e-4f
#define INV256  0.00390625f
#define SSTR 144   // stage tile row stride (halfs)

__device__ __forceinline__ float swap8(float x){
  return __int_as_float(
    __builtin_amdgcn_mov_dpp(__float_as_int(x), 0x128, 0xf, 0xf, true));
}

struct Tab {
  double a[7][7]; double b[7]; double A[7]; double XC[7][7]; double XF[7]; double cxc[7];
};
static constexpr Tab make_tab() {
  Tab t{};
  t.a[2][1]=1.0/5;
  t.a[3][1]=3.0/40;       t.a[3][2]=9.0/40;
  t.a[4][1]=44.0/45;      t.a[4][2]=-56.0/15;      t.a[4][3]=32.0/9;
  t.a[5][1]=19372.0/6561; t.a[5][2]=-25360.0/2187; t.a[5][3]=64448.0/6561; t.a[5][4]=-212.0/729;
  t.a[6][1]=9017.0/3168;  t.a[6][2]=-355.0/33;     t.a[6][3]=46732.0/5247; t.a[6][4]=49.0/176; t.a[6][5]=-5103.0/18656;
  t.b[1]=35.0/384; t.b[2]=0.0; t.b[3]=500.0/1113; t.b[4]=125.0/192; t.b[5]=-2187.0/6784; t.b[6]=11.0/84;
  for (int i=1;i<=6;++i){ double s=0; for(int j=1;j<i;++j) s+=t.a[i][j]; t.A[i]=s; }
  for (int i=1;i<=6;++i) for(int l=1;l<i;++l){ double s=0; for(int j=l+1;j<i;++j) s+=t.a[i][j]*t.a[j][l]; t.XC[i][l]=s; }
  for (int i=1;i<=6;++i){ double s=0; for(int j=1;j<i;++j) s+=t.a[i][j]*t.A[j]; t.XF[i]=s; }
  for (int j=1;j<=6;++j){ double s=0; for (int i=j+1;i<=6;++i) s+=t.b[i]*t.a[i][j]; t.cxc[j]=s; }
  return t;
}
static constexpr Tab TB = make_tab();

__device__ __forceinline__ int decode_steps(const void* p){
  int v = *(const int*)p;
  if (v >= 1 && v <= 512) return v;
  float f = *(const float*)p;
  if (f >= 1.f && f <= 512.f) return (int)f;
  return 8;
}
__device__ __forceinline__ void split2s(float x, _Float16& h, _Float16& l){
  h = (_Float16)x;
  l = (_Float16)((x - (float)h) * 2048.0f);
}

#define WS_GH 0
#define WS_GL 16384
#define WS_UH 32768
#define WS_UL 98304
#define WS_WH 163840
#define WS_WL 229376

// ---- fused prep: blocks 0-7 = G' GEMM from raw U/W; blocks 8-263 = repack ----
__global__ __launch_bounds__(512) void k_prep(const float* __restrict__ Ug,
                                              const float* __restrict__ Wg,
                                              _Float16* __restrict__ ws){
  const int tid = threadIdx.x;
  if (blockIdx.x >= 8) {
    int t = (blockIdx.x - 8)*512 + tid;
    if (t < 65536) {
      int r = t >> 7, c = t & 127;
      _Float16 h, l; split2s(Ug[t]*256.f, h, l);
      int kb=r>>5, q2=(r>>3)&3, j=r&7, n2=c>>4, cl=c&15;
      int slot = ((n2*16+kb)*64 + q2*16+cl)*8 + j;
      ws[WS_UH + slot] = h; ws[WS_UL + slot] = l;
    } else {
      int idx = t - 65536;
      int r = idx >> 9, c = idx & 511;
      _Float16 h, l; split2s(Wg[idx]*256.f, h, l);
      int kb=r>>5, q2=(r>>3)&3, j=r&7, n2=c>>4, cl=c&15;
      int slot = ((n2*4+kb)*64 + q2*16+cl)*8 + j;
      ws[WS_WH + slot] = h; ws[WS_WL + slot] = l;
    }
  } else {
    const int b = blockIdx.x;
    const int ww = tid >> 6, lane = tid & 63, q = lane >> 4, c16 = lane & 15;
    const int nb = ww;
    v4f aH = {0,0,0,0}, aC0 = {0,0,0,0}, aC1 = {0,0,0,0};
    #pragma unroll
    for (int kb = 0; kb < 16; ++kb) {
      const float* wp = Wg + (b*16 + c16)*512 + kb*32 + q*8;
      float4 w0 = *(const float4*)wp;
      float4 w1 = *(const float4*)(wp + 4);
      float wv[8] = {w0.x,w0.y,w0.z,w0.w, w1.x,w1.y,w1.z,w1.w};
      v8h Ah, Al, Bh, Bl;
      #pragma unroll
      for (int j = 0; j < 8; ++j) {
        _Float16 h, l; split2s(-wv[j], h, l);
        Ah[j] = h; Al[j] = l;
        float uv = Ug[(kb*32 + q*8 + j)*128 + nb*16 + c16] * 256.f;
        split2s(uv, h, l);
        Bh[j] = h; Bl[j] = l;
      }
      aH = MFMAH(Ah, Bh, aH, 0,0,0);
      if (kb & 1) {
        aC1 = MFMAH(Ah, Bl, aC1, 0,0,0);
        aC1 = MFMAH(Al, Bh, aC1, 0,0,0);
      } else {
        aC0 = MFMAH(Ah, Bl, aC0, 0,0,0);
        aC0 = MFMAH(Al, Bh, aC0, 0,0,0);
      }
    }
    #pragma unroll
    for (int r = 0; r < 4; ++r) {
      float g = aH[r] + (aC0[r] + aC1[r])*INV2048;
      _Float16 h, l; split2s(g, h, l);
      int m = b*16 + 4*q + r, n = nb*16 + c16;
      int slot = (((n>>4)*4 + (m>>5))*64 + ((m>>3)&3)*16 + (n&15))*8 + (m&7);
      ws[WS_GH + slot] = h; ws[WS_GL + slot] = l;
    }
  }
}

// arena: projection tiles 2 * 24*520 halfs = 49920 B (tH base, tL +12480h).
// bounce T: 3 x 1056 f32 = 12672 B at base (after projection reads done).
// recursion bT dbuf: 2 x 2304 halfs = 9216 B at base.
// epilogue: RQ tiles base..8704 B; axs @9216 (16KB), abs @25600 (16KB).
#define ARENA 49920

__global__ __launch_bounds__(256,2) void dp5_main(
    const float* __restrict__ xg, const float* __restrict__ vg,
    const float* __restrict__ fg, const void* stepsp,
    const _Float16* __restrict__ ws, float* __restrict__ outg)
{
  __shared__ __align__(16) char arena[ARENA];
  _Float16* base = (_Float16*)arena;
  const _Float16* uH = ws + WS_UH;
  const _Float16* uL = ws + WS_UL;
  const _Float16* wH = ws + WS_WH;
  const _Float16* wL = ws + WS_WL;

  if (blockIdx.x & 256) __builtin_amdgcn_s_sleep(19);

  const int tid  = threadIdx.x;
  const int w    = tid >> 6;          // warp 0..3
  const int lane = tid & 63;
  const int q    = lane >> 4;
  const int c16  = lane & 15;
  const int rb   = blockIdx.x * 8;
  const int S    = decode_steps(stepsp);
  const float dt = 0.01f;
  const int  brow = c16 & 7;
  const bool hiC  = (c16 >= 8);
  // lane owns 4 consecutive P-cols: group (w, hiC), quad q
  const int  kc0n = w*32 + (hiC ? 16 : 0) + 4*q;

  // ---- merged projections: stage 24x512 tile (x rows 0-7, v 8-15, f 16-23)
  _Float16* tH = base;
  _Float16* tL = base + 12480;
  {
    const int row = tid >> 4;            // 0..15
    const int c0  = (tid & 15) * 32;
    {
      const float* sp = (row < 8) ? (xg + (rb + row)*512) : (vg + (rb + row - 8)*512);
      sp += c0;
      #pragma unroll
      for (int b2 = 0; b2 < 4; ++b2) {
        float4 g0 = *(const float4*)(sp + b2*8);
        float4 g1 = *(const float4*)(sp + b2*8 + 4);
        float vals[8] = {g0.x,g0.y,g0.z,g0.w, g1.x,g1.y,g1.z,g1.w};
        v8h vh, vl;
        #pragma unroll
        for (int j = 0; j < 8; ++j) { _Float16 h,l; split2s(vals[j],h,l); vh[j]=h; vl[j]=l; }
        int o = row*520 + c0 + b2*8;
        *(v8h*)(tH + o) = vh; *(v8h*)(tL + o) = vl;
      }
    }
    if (tid < 128) {
      const int rowf = tid >> 4;         // 0..7
      const float* sp = fg + (rb + rowf)*512 + c0;
      #pragma unroll
      for (int b2 = 0; b2 < 4; ++b2) {
        float4 g0 = *(const float4*)(sp + b2*8);
        float4 g1 = *(const float4*)(sp + b2*8 + 4);
        float vals[8] = {g0.x,g0.y,g0.z,g0.w, g1.x,g1.y,g1.z,g1.w};
        v8h vh, vl;
        #pragma unroll
        for (int j = 0; j < 8; ++j) { _Float16 h,l; split2s(vals[j],h,l); vh[j]=h; vl[j]=l; }
        int o = (16 + rowf)*520 + c0 + b2*8;
        *(v8h*)(tH + o) = vh; *(v8h*)(tL + o) = vl;
      }
    }
  }
  __syncthreads();

  // ---- projection GEMM: per warp, 2 col-groups (nb = 2w, 2w+1) ----
  float cxU4[4], cvU4[4], fU4[4];
  {
    v4f AH0[2],AH1[2],AC0[2],AC1[2],BH0[2],BH1[2],BC0[2],BC1[2];
    #pragma unroll
    for (int g=0; g<2; ++g){
      AH0[g]=v4f{0,0,0,0}; AH1[g]=v4f{0,0,0,0}; AC0[g]=v4f{0,0,0,0}; AC1[g]=v4f{0,0,0,0};
      BH0[g]=v4f{0,0,0,0}; BH1[g]=v4f{0,0,0,0}; BC0[g]=v4f{0,0,0,0}; BC1[g]=v4f{0,0,0,0};
    }
    const int arow1 = (c16 < 8) ? (16 + c16) : c16;
    #pragma unroll
    for (int kb = 0; kb < 16; ++kb) {
      int ao0 = c16*520 + kb*32 + q*8;
      int ao1 = arow1*520 + kb*32 + q*8;
      v8h Ah0 = *(const v8h*)(tH + ao0);
      v8h Al0 = *(const v8h*)(tL + ao0);
      v8h Ah1 = *(const v8h*)(tH + ao1);
      v8h Al1 = *(const v8h*)(tL + ao1);
      #pragma unroll
      for (int g = 0; g < 2; ++g) {
        int bo = (((2*w+g)*16 + kb)*64 + lane)*8;
        v8h Bh = *(const v8h*)(uH + bo);
        v8h Bl = *(const v8h*)(uL + bo);
        if (kb & 1) {
          AH1[g] = MFMAH(Ah0, Bh, AH1[g], 0,0,0);
          AC1[g] = MFMAH(Ah0, Bl, AC1[g], 0,0,0);
          AC1[g] = MFMAH(Al0, Bh, AC1[g], 0,0,0);
          BH1[g] = MFMAH(Ah1, Bh, BH1[g], 0,0,0);
          BC1[g] = MFMAH(Ah1, Bl, BC1[g], 0,0,0);
          BC1[g] = MFMAH(Al1, Bh, BC1[g], 0,0,0);
        } else {
          AH0[g] = MFMAH(Ah0, Bh, AH0[g], 0,0,0);
          AC0[g] = MFMAH(Ah0, Bl, AC0[g], 0,0,0);
          AC0[g] = MFMAH(Al0, Bh, AC0[g], 0,0,0);
          BH0[g] = MFMAH(Ah1, Bh, BH0[g], 0,0,0);
          BC0[g] = MFMAH(Ah1, Bl, BC0[g], 0,0,0);
          BC0[g] = MFMAH(Al1, Bh, BC0[g], 0,0,0);
        }
      }
    }
    __syncthreads();   // projection-tile reads done; T overlays tH region
    // ---- T-write, CORRECTED routing ----
    // reg r of group g at lane (q,c16) = proj[tile_row 4q+r][col (2w+g)*16+c16]
    // tile rows: a-chain 0-7=x, 8-15=v; b-chain (q<2) rows = f 0-7.
    float* T = (float*)arena;   // T_x @0, T_v @1056, T_f @2112 (f32 idx)
    #pragma unroll
    for (int g = 0; g < 2; ++g) {
      float ar[4], br[4];
      #pragma unroll
      for (int r = 0; r < 4; ++r) {
        ar[r] = ((AH0[g][r]+AH1[g][r]) + (AC0[g][r]+AC1[g][r])*INV2048)*INV256;
        br[r] = ((BH0[g][r]+BH1[g][r]) + (BC0[g][r]+BC1[g][r])*INV2048)*INV256;
      }
      int colc = (2*w+g)*16 + c16;
      if (q < 2) {
        #pragma unroll
        for (int r = 0; r < 4; ++r) {
          T[(4*q+r)*132 + colc]        = ar[r];   // x rows 4q+r
          T[2112 + (4*q+r)*132 + colc] = br[r];   // f rows 4q+r
        }
      } else {
        #pragma unroll
        for (int r = 0; r < 4; ++r) {
          T[1056 + (4*(q-2)+r)*132 + colc] = ar[r];  // v rows 4(q-2)+r
        }
      }
    }
    __syncthreads();
    float4 tx = *(const float4*)(T +        brow*132 + kc0n);
    float4 tv = *(const float4*)(T + 1056 + brow*132 + kc0n);
    float4 tf = *(const float4*)(T + 2112 + brow*132 + kc0n);
    cxU4[0]=tx.x; cxU4[1]=tx.y; cxU4[2]=tx.z; cxU4[3]=tx.w;
    cvU4[0]=tv.x; cvU4[1]=tv.y; cvU4[2]=tv.z; cvU4[3]=tv.w;
    fU4[0]=tf.x;  fU4[1]=tf.y;  fU4[2]=tf.z;  fU4[3]=tf.w;
    __syncthreads();   // T region freed before bT writes
  }

  // G fragments: 2 groups x 4 kb
  v8h Gh[2][4], Gl[2][4];
  #pragma unroll
  for (int g = 0; g < 2; ++g)
    #pragma unroll
    for (int kb = 0; kb < 4; ++kb) {
      int off = (((2*w+g)*4 + kb)*64 + lane)*8;
      Gh[g][kb] = *(const v8h*)(ws + WS_GH + off);
      Gl[g][kb] = *(const v8h*)(ws + WS_GL + off);
    }

  // ---- rank-128 recursion: 4 cols/lane ----
  float kU[6][4], Rr[4], QX[4];
  #pragma unroll
  for (int j = 0; j < 4; ++j) {
    Rr[j] = 0.f; QX[j] = 0.f;
    #pragma unroll
    for (int l = 0; l < 6; ++l) kU[l][j] = 0.f;
  }

  int pb = 0;
  for (int s = 0; s < S; ++s) {
    float accX[4], accV[4], Pb[4], Pxc[4];
    #pragma unroll
    for (int j = 0; j < 4; ++j) { accX[j]=0.f; accV[j]=0.f; Pb[j]=0.f; Pxc[j]=0.f; }

    #pragma unroll
    for (int i = 1; i <= 6; ++i) {
      _Float16* bT = base + (pb ? 2304 : 0);
      const float dtA   = dt*(float)TB.A[i];
      const float dt2XF = dt*dt*(float)TB.XF[i];
      const float bi    = (float)TB.b[i];
      const float ci    = (float)TB.cxc[i];
      // phase1: 4 cols per lane, packed b64 writes
      {
        union { _Float16 h[4]; u64 u; } ph, pl;
        #pragma unroll
        for (int j2 = 0; j2 < 4; ++j2) {
          float vv = cvU4[j2] + dtA*fU4[j2];
          float xx = cxU4[j2] + dtA*cvU4[j2] + dt2XF*fU4[j2];
          #pragma unroll
          for (int l = 1; l < i; ++l) {
            vv += (dt*(float)TB.a[i][l]) * kU[l-1][j2];
            xx += (dt*dt*(float)TB.XC[i][l]) * kU[l-1][j2];
          }
          float p = vv*xx;
          Pb[j2] += bi*p; Pxc[j2] += ci*p;
          _Float16 h, l2; split2s(p, h, l2);
          ph.h[j2] = h; pl.h[j2] = l2;
        }
        *(u64*)(bT + brow*SSTR + kc0n)     = ph.u;   // Ph rows 0-7
        *(u64*)(bT + (8+brow)*SSTR + kc0n) = pl.u;   // Pl rows 8-15
      }
      __syncthreads();
      const _Float16* bp = bT + c16*SSTR + q*8;
      v8h B0 = *(const v8h*)(bp);
      v8h B1 = *(const v8h*)(bp + 32);
      v8h B2 = *(const v8h*)(bp + 64);
      v8h B3 = *(const v8h*)(bp + 96);
      v4f C1[2], C2[2];
      #pragma unroll
      for (int g = 0; g < 2; ++g) {
        C1[g] = v4f{0,0,0,0}; C2[g] = v4f{0,0,0,0};
        C1[g] = MFMAH(Gh[g][0], B0, C1[g], 0,0,0);  C2[g] = MFMAH(Gl[g][0], B0, C2[g], 0,0,0);
        C1[g] = MFMAH(Gh[g][1], B1, C1[g], 0,0,0);  C2[g] = MFMAH(Gl[g][1], B1, C2[g], 0,0,0);
        C1[g] = MFMAH(Gh[g][2], B2, C1[g], 0,0,0);  C2[g] = MFMAH(Gl[g][2], B2, C2[g], 0,0,0);
        C1[g] = MFMAH(Gh[g][3], B3, C1[g], 0,0,0);  C2[g] = MFMAH(Gl[g][3], B3, C2[g], 0,0,0);
      }
      // combine: kv per group (valid on c16<8), route group-1 to hiC lanes
      #pragma unroll
      for (int r = 0; r < 4; ++r) {
        float kv0 = (C1[0][r] + (swap8(C1[0][r]) + C2[0][r])*INV2048)*INV256;
        float kv1 = (C1[1][r] + (swap8(C1[1][r]) + C2[1][r])*INV2048)*INV256;
        float sk1 = swap8(kv1);
        float kk  = hiC ? sk1 : kv0;
        kU[i-1][r] = kk;
        accX[r] += ci*kk; accV[r] += bi*kk;
      }
      pb ^= 1;
    }

    #pragma unroll
    for (int j = 0; j < 4; ++j) {
      float nx = cxU4[j] + dt*cvU4[j] + dt*dt*(accX[j] + 0.5f*fU4[j]);
      cvU4[j] += dt*(accV[j] + fU4[j]);
      cxU4[j]  = nx;
      QX[j] += Rr[j] + Pxc[j];
      Rr[j] += Pb[j];
    }
  }

  // ---- epilogue: fill R|QX tiles (rows 0-7 R, 8-15 QX; h/l buffers) ----
  __syncthreads();
  _Float16* RQh = base;
  _Float16* RQl = base + 2176;
  {
    union { _Float16 h[4]; u64 u; } t1, t2, t3, t4;
    #pragma unroll
    for (int j2 = 0; j2 < 4; ++j2) {
      _Float16 h, l;
      split2s(Rr[j2], h, l);  t1.h[j2] = h; t2.h[j2] = l;
      split2s(QX[j2], h, l);  t3.h[j2] = h; t4.h[j2] = l;
    }
    *(u64*)(RQh + brow*136 + kc0n)     = t1.u;
    *(u64*)(RQl + brow*136 + kc0n)     = t2.u;
    *(u64*)(RQh + (8+brow)*136 + kc0n) = t3.u;
    *(u64*)(RQl + (8+brow)*136 + kc0n) = t4.u;
  }
  __syncthreads();

  v8h EAh[4], EAl[4];
  #pragma unroll
  for (int kb = 0; kb < 4; ++kb) {
    int ao = c16*136 + kb*32 + q*8;
    EAh[kb] = *(const v8h*)(RQh + ao);
    EAl[kb] = *(const v8h*)(RQl + ao);
  }

  float* axs  = (float*)(arena + 9216);
  float* abs_ = (float*)(arena + 25600);

  #pragma unroll
  for (int g = 0; g < 2; ++g) {
    #pragma unroll
    for (int cbi = 0; cbi < 4; ++cbi) {
      int cb = (2*w+g)*4 + cbi;
      v4f aH={0,0,0,0}, aC0={0,0,0,0}, aC1={0,0,0,0};
      #pragma unroll
      for (int kb = 0; kb < 4; ++kb) {
        int bo = ((cb*4 + kb)*64 + lane)*8;
        v8h Bh = *(const v8h*)(wH + bo);
        v8h Bl = *(const v8h*)(wL + bo);
        aH = MFMAH(EAh[kb], Bh, aH, 0,0,0);
        if (kb & 1) {
          aC1 = MFMAH(EAh[kb], Bl, aC1, 0,0,0);
          aC1 = MFMAH(EAl[kb], Bh, aC1, 0,0,0);
        } else {
          aC0 = MFMAH(EAh[kb], Bl, aC0, 0,0,0);
          aC0 = MFMAH(EAl[kb], Bh, aC0, 0,0,0);
        }
      }
      float r0 = (aH[0] + (aC0[0]+aC1[0])*INV2048)*INV256;
      float r1 = (aH[1] + (aC0[1]+aC1[1])*INV2048)*INV256;
      float r2 = (aH[2] + (aC0[2]+aC1[2])*INV2048)*INV256;
      float r3 = (aH[3] + (aC0[3]+aC1[3])*INV2048)*INV256;
      float o0 = __shfl_xor(r0, 32, 64);
      float o1 = __shfl_xor(r1, 32, 64);
      float o2 = __shfl_xor(r2, 32, 64);
      float o3 = __shfl_xor(r3, 32, 64);
      if (q < 2) {
        float abv[4] = {r0, r1, r2, r3};
        float axv[4] = {o0, o1, o2, o3};
        #pragma unroll
        for (int i4 = 0; i4 < 4; ++i4) {
          int lrow = 4*q + i4;
          int lcol = cb*16 + c16;
          axs[lrow*512 + lcol]  = axv[i4];
          abs_[lrow*512 + lcol] = abv[i4];
        }
      }
    }
  }
  __syncthreads();

  // coalesced drain: 256 threads x 4 chunks
  const float Sdt = (float)S * dt;
  #pragma unroll
  for (int half = 0; half < 4; ++half) {
    int flat = half*1024 + tid*4;            // 0..4095, step 4
    int row  = flat >> 9;                    // 0..7
    int col  = flat & 511;
    int go   = (rb + row)*512 + col;
    float4 xv = *(const float4*)(xg + go);
    float4 vv = *(const float4*)(vg + go);
    float4 fv = *(const float4*)(fg + go);
    float4 axf = *(const float4*)(axs + flat);
    float4 abf = *(const float4*)(abs_ + flat);
    float4 o1, o2;
    o1.x = xv.x + Sdt*vv.x + 0.5f*Sdt*Sdt*fv.x - dt*dt*axf.x;
    o1.y = xv.y + Sdt*vv.y + 0.5f*Sdt*Sdt*fv.y - dt*dt*axf.y;
    o1.z = xv.z + Sdt*vv.z + 0.5f*Sdt*Sdt*fv.z - dt*dt*axf.z;
    o1.w = xv.w + Sdt*vv.w + 0.5f*Sdt*Sdt*fv.w - dt*dt*axf.w;
    o2.x = vv.x + Sdt*fv.x - dt*abf.x;
    o2.y = vv.y + Sdt*fv.y - dt*abf.y;
    o2.z = vv.z + Sdt*fv.z - dt*abf.z;
    o2.w = vv.w + Sdt*fv.w - dt*abf.w;
    *(float4*)(outg + go) = o1;
    *(float4*)(outg + 2097152 + go) = o2;
  }
}

extern "C" void kernel_launch(void* const* d_in, const int* in_sizes, int n_in,
                              void* d_out, int out_size, void* d_ws, size_t ws_size,
                              hipStream_t stream) {
  const float* x = (const float*)d_in[0];
  const float* v = (const float*)d_in[1];
  const float* f = (const float*)d_in[2];
  const float* U = (const float*)d_in[3];
  const float* W = (const float*)d_in[4];
  _Float16* ws = (_Float16*)d_ws;

  k_prep<<<dim3(264), dim3(512), 0, stream>>>(U, W, ws);
  dp5_main<<<dim3(512), dim3(256), 0, stream>>>(
      x, v, f, d_in[5], ws, (float*)d_out);
}